// Round 6
// baseline (333.315 us; speedup 1.0000x reference)
//
#include <hip/hip_runtime.h>
#include <hip/hip_bf16.h>

#define D_FEAT 256

typedef __attribute__((ext_vector_type(8))) __bf16 bf16x8;
typedef __attribute__((ext_vector_type(4))) __bf16 bf16x4;
typedef __attribute__((ext_vector_type(4))) float f32x4;

// ---------------------------------------------------------------------------
// Kernel 0: Wt[n][k] = bf16(W[k][n])   (256x256, tiny)
// ---------------------------------------------------------------------------
__global__ __launch_bounds__(256) void cast_wt(
    const float* __restrict__ W, __bf16* __restrict__ Wt) {
  const int n = blockIdx.x;
  const int k = threadIdx.x;
  Wt[n * 256 + k] = (__bf16)W[k * 256 + n];
}

// ---------------------------------------------------------------------------
// Kernel 1: S = bf16( X @ W )  via mfma_f32_16x16x32_bf16
// Tile BM=128, BN=128, BK=32; operands SWAPPED (A=Wt rows, B=X rows) so the
// D reg-dim runs along n -> epilogue packs 4 consecutive bf16 per 8B store.
// ---------------------------------------------------------------------------
#define APITCH 40  // bf16 elems per row (pad 32->40; 2-way LDS alias = free)

__global__ __launch_bounds__(256) void gemm_mfma(
    const float* __restrict__ X, const __bf16* __restrict__ Wt,
    __bf16* __restrict__ S, int M) {
  __shared__ __bf16 As[128 * APITCH];  // 10 KiB
  __shared__ __bf16 Bs[128 * APITCH];  // 10 KiB
  const int tid = threadIdx.x;
  const int wave = tid >> 6;
  const int lane = tid & 63;
  const int m0 = blockIdx.y * 128;
  const int n0 = blockIdx.x * 128;

  f32x4 acc[2][8] = {};

  const int l15 = lane & 15;
  const int kh8 = (lane >> 4) * 8;

  const int r = tid >> 1;            // 0..127
  const int kh = (tid & 1) * 16;     // 0 or 16
  const int gr = m0 + r;
  const bool valid = gr < M;
  const float* xsrc = X + (size_t)(valid ? gr : 0) * D_FEAT + kh;

  float4 pre[4];
#pragma unroll
  for (int q = 0; q < 4; ++q)
    pre[q] = valid ? *reinterpret_cast<const float4*>(xsrc + q * 4)
                   : make_float4(0.f, 0.f, 0.f, 0.f);

  const int nr = tid >> 1;           // B staging: 0..127
  const int qb = (tid & 1) * 16;     // 0 or 16

  for (int k0 = 0; k0 < D_FEAT; k0 += 32) {
    const __bf16* wsrc = Wt + (size_t)(n0 + nr) * D_FEAT + k0 + qb;
    bf16x8 wb0 = *reinterpret_cast<const bf16x8*>(wsrc);
    bf16x8 wb1 = *reinterpret_cast<const bf16x8*>(wsrc + 8);

    bf16x8 a0, a1;
    a0[0] = (__bf16)pre[0].x; a0[1] = (__bf16)pre[0].y;
    a0[2] = (__bf16)pre[0].z; a0[3] = (__bf16)pre[0].w;
    a0[4] = (__bf16)pre[1].x; a0[5] = (__bf16)pre[1].y;
    a0[6] = (__bf16)pre[1].z; a0[7] = (__bf16)pre[1].w;
    a1[0] = (__bf16)pre[2].x; a1[1] = (__bf16)pre[2].y;
    a1[2] = (__bf16)pre[2].z; a1[3] = (__bf16)pre[2].w;
    a1[4] = (__bf16)pre[3].x; a1[5] = (__bf16)pre[3].y;
    a1[6] = (__bf16)pre[3].z; a1[7] = (__bf16)pre[3].w;
    *reinterpret_cast<bf16x8*>(&As[r * APITCH + kh]) = a0;
    *reinterpret_cast<bf16x8*>(&As[r * APITCH + kh + 8]) = a1;
    *reinterpret_cast<bf16x8*>(&Bs[nr * APITCH + qb]) = wb0;
    *reinterpret_cast<bf16x8*>(&Bs[nr * APITCH + qb + 8]) = wb1;

    const bool have = (k0 + 32) < D_FEAT;
    float4 nxt[4];
    if (have && valid) {
#pragma unroll
      for (int q = 0; q < 4; ++q)
        nxt[q] = *reinterpret_cast<const float4*>(xsrc + k0 + 32 + q * 4);
    }
    __syncthreads();

    bf16x8 a[2], b[8];
#pragma unroll
    for (int rg = 0; rg < 2; ++rg)
      a[rg] = *reinterpret_cast<const bf16x8*>(
          &As[(wave * 32 + rg * 16 + l15) * APITCH + kh8]);
#pragma unroll
    for (int cg = 0; cg < 8; ++cg)
      b[cg] = *reinterpret_cast<const bf16x8*>(
          &Bs[(cg * 16 + l15) * APITCH + kh8]);
    // Operands swapped: A = Wt rows (n dim), B = X rows (m dim).
    // D: n = (l>>4)*4 + reg, m = l&15.
#pragma unroll
    for (int rg = 0; rg < 2; ++rg)
#pragma unroll
      for (int cg = 0; cg < 8; ++cg)
        acc[rg][cg] = __builtin_amdgcn_mfma_f32_16x16x32_bf16(
            b[cg], a[rg], acc[rg][cg], 0, 0, 0);
    __syncthreads();

    if (have && valid) {
#pragma unroll
      for (int q = 0; q < 4; ++q) pre[q] = nxt[q];
    }
  }

  // epilogue: lane writes 4 consecutive n as one 8B bf16x4 store
#pragma unroll
  for (int rg = 0; rg < 2; ++rg) {
    const int m = m0 + wave * 32 + rg * 16 + l15;
    if (m < M) {
#pragma unroll
      for (int cg = 0; cg < 8; ++cg) {
        const int nb = n0 + cg * 16 + (lane >> 4) * 4;
        bf16x4 p;
#pragma unroll
        for (int rr = 0; rr < 4; ++rr) p[rr] = (__bf16)acc[rg][cg][rr];
        *reinterpret_cast<bf16x4*>(&S[(size_t)m * D_FEAT + nb]) = p;
      }
    }
  }
}

// ---------------------------------------------------------------------------
// Kernel 2: rowptr via binary search on sorted adj_row
// ---------------------------------------------------------------------------
__global__ __launch_bounds__(256) void build_rowptr(
    const int* __restrict__ rows, int E, int* __restrict__ ptr, int N) {
  const int n = blockIdx.x * blockDim.x + threadIdx.x;
  if (n > N) return;
  int lo = 0, hi = E;
  while (lo < hi) {
    const int mid = (lo + hi) >> 1;
    if (rows[mid] < n) lo = mid + 1; else hi = mid;
  }
  ptr[n] = lo;
}

// ---------------------------------------------------------------------------
// Kernel 3: out[n] = bias + sum val[e]*S[col[e]]
// Wave per node; half-wave h = edges of parity h; lane = 8 feats (16B).
// Rotating 8-slot software pipeline: consuming slot i of batch b issues
// slot i's gather for batch b+1 -> 8 KB permanently in flight per wave,
// FMA chain overlaps gather latency. 32-bit saddr offsets.
// ---------------------------------------------------------------------------
__global__ __launch_bounds__(256) void spmm_rows(
    const __bf16* __restrict__ S, const int* __restrict__ ptr,
    const int* __restrict__ col, const float* __restrict__ val,
    const float* __restrict__ bias, float* __restrict__ out, int N) {
  const int wave = threadIdx.x >> 6;
  const int lane = threadIdx.x & 63;
  const int n = blockIdx.x * 4 + wave;
  if (n >= N) return;

  const int e0 = ptr[n];
  const int e1 = ptr[n + 1];
  const int hw = lane >> 5;                 // 0: even edges, 1: odd edges
  const uint32_t foff = (lane & 31) * 16;   // byte offset of feature group
  const char* Sb = (const char*)S;

  const int elast = e1 - 1;
  const int esafe = elast >= 0 ? elast : 0;

  float acc[8] = {};
  float vv[8];
  bf16x8 g[8];

  // prologue: batch 0 (clamped full batch)
#pragma unroll
  for (int i = 0; i < 8; ++i) {
    int ee = e0 + 2 * i + hw;
    const bool ok = ee <= elast;
    ee = ok ? ee : esafe;
    const int c = col[ee];
    vv[i] = ok ? val[ee] : 0.f;
    g[i] = *reinterpret_cast<const bf16x8*>(Sb + (((uint32_t)c << 9) + foff));
  }

  int base = e0;
  for (; base + 16 < e1; base += 16) {
    const int nb = base + 16;
#pragma unroll
    for (int i = 0; i < 8; ++i) {
      const float v = vv[i];
      const bf16x8 s = g[i];
      // reload slot i for next batch (issues while we consume s)
      int ee = nb + 2 * i + hw;
      const bool ok = ee <= elast;
      ee = ok ? ee : esafe;
      const int c = col[ee];
      vv[i] = ok ? val[ee] : 0.f;
      g[i] = *reinterpret_cast<const bf16x8*>(Sb + (((uint32_t)c << 9) + foff));
#pragma unroll
      for (int j = 0; j < 8; ++j) acc[j] += v * (float)s[j];
    }
  }
  // final batch: consume without reload
#pragma unroll
  for (int i = 0; i < 8; ++i) {
    const float v = vv[i];
    const bf16x8 s = g[i];
#pragma unroll
    for (int j = 0; j < 8; ++j) acc[j] += v * (float)s[j];
  }

  // combine half-waves: partner lane is lane ^ 32
#pragma unroll
  for (int j = 0; j < 8; ++j) acc[j] += __shfl(acc[j], lane ^ 32, 64);

  // lane (hw, l5) writes float4 at feature (l5*8 + hw*4)
  const int fw = (lane & 31) * 8 + hw * 4;
  const float4 b = *reinterpret_cast<const float4*>(bias + fw);
  const float r0 = hw ? acc[4] : acc[0];
  const float r1 = hw ? acc[5] : acc[1];
  const float r2 = hw ? acc[6] : acc[2];
  const float r3 = hw ? acc[7] : acc[3];
  f32x4 o;
  o[0] = r0 + b.x; o[1] = r1 + b.y; o[2] = r2 + b.z; o[3] = r3 + b.w;
  __builtin_nontemporal_store(
      o, reinterpret_cast<f32x4*>(out + (size_t)n * D_FEAT + fw));
}

// ---------------------------------------------------------------------------
extern "C" void kernel_launch(void* const* d_in, const int* in_sizes, int n_in,
                              void* d_out, int out_size, void* d_ws, size_t ws_size,
                              hipStream_t stream) {
  const float* x       = (const float*)d_in[0];
  const int*   adj_row = (const int*)d_in[1];
  const int*   adj_col = (const int*)d_in[2];
  const float* adj_val = (const float*)d_in[3];
  const float* weight  = (const float*)d_in[4];
  const float* bias    = (const float*)d_in[5];
  float*       out     = (float*)d_out;

  const int N = in_sizes[0] / D_FEAT;   // 100000
  const int E = in_sizes[1];            // 3200000

  // ws layout: Wt bf16 [256*256] | support bf16 [N*256] | rowptr int [N+1]
  __bf16* Wt      = (__bf16*)d_ws;
  __bf16* support = Wt + 256 * 256;
  int*    rowptr  = (int*)(support + (size_t)N * D_FEAT);

  cast_wt<<<256, 256, 0, stream>>>(weight, Wt);

  {
    dim3 grid(D_FEAT / 128, (N + 127) / 128);
    gemm_mfma<<<grid, 256, 0, stream>>>(x, Wt, support, N);
  }
  {
    const int threads = 256;
    const int blocks = (N + 1 + threads - 1) / threads;
    build_rowptr<<<blocks, threads, 0, stream>>>(adj_row, E, rowptr, N);
  }
  {
    const int blocks = (N + 3) / 4;
    spmm_rows<<<blocks, 256, 0, stream>>>(support, rowptr, adj_col, adj_val,
                                          bias, out, N);
  }
}